// Round 1
// baseline (434.764 us; speedup 1.0000x reference)
//
#include <hip/hip_runtime.h>

// InterConv: B=2048, F=39, E=64, C=64, P = F*(F-1)/2 = 741
// out[b*(C*P) + c*P + p] = relu( x[b,ii[p]]·Wi[c] + x[b,jj[p]]·Wj[c] + bias[c] )
//
// Fused one-kernel design: block = one batch b, 256 threads.
//  phase 0: stage xT[e][f] (stride 40) and Wl[e][cw] (stride 132) into LDS,
//           build pair table, stage bias.
//  phase 1: per-thread 5f x 4cw register-tile GEMM (K=64) -> acc in VGPRs.
//  phase 1.5: write A[cw][f] (stride 41) into LDS (aliases staging region).
//  phase 2: gather-add-relu, coalesced b32 stores.

#define BATCH 2048
#define FDIM  39
#define EDIM  64
#define CDIM  64
#define NPAIR 741
#define XSTR  40    // xT leading-dim pad (f padded 39->40)
#define WSTR  132   // Wl leading-dim pad (128+4, keeps float4 alignment)
#define ASTR  41    // A leading-dim pad (odd stride -> spread banks)

__global__ __launch_bounds__(256) void interconv_fused(
    const float* __restrict__ x,     // [B, F, E]
    const float* __restrict__ Wg,    // [C, 1, 2, E] flat: c*128 + which*64 + e
    const float* __restrict__ bias,  // [C]
    float* __restrict__ out)         // [B, C*P] with layout c*P + p
{
    __shared__ float smem[EDIM * XSTR + EDIM * WSTR]; // 2560 + 8448 = 11008 floats (44032 B)
    __shared__ int   tab[NPAIR];
    __shared__ float sbias[CDIM];

    float* xT = smem;               // [EDIM][XSTR]
    float* Wl = smem + EDIM * XSTR; // [EDIM][WSTR]
    float* A  = smem;               // [128][ASTR] = 5248 floats, aliases staging (after barrier)

    const int tid = threadIdx.x;
    const int b   = blockIdx.x;
    const float* xg = x + (size_t)b * (FDIM * EDIM);

    // ---- phase 0: staging ----
    // x: 2496 floats = 624 float4, transpose into xT[e][f]
    for (int q = tid; q < (FDIM * EDIM) / 4; q += 256) {
        float4 v = ((const float4*)xg)[q];
        int flat = q << 2;
        int f  = flat >> 6;
        int e0 = flat & 63;
        xT[(e0 + 0) * XSTR + f] = v.x;
        xT[(e0 + 1) * XSTR + f] = v.y;
        xT[(e0 + 2) * XSTR + f] = v.z;
        xT[(e0 + 3) * XSTR + f] = v.w;
    }
    // W: 8192 floats = 2048 float4, into Wl[e][cw], cw = which*64 + c
    for (int q = tid; q < (CDIM * 2 * EDIM) / 4; q += 256) {
        float4 v = ((const float4*)Wg)[q];
        int flat = q << 2;
        int c   = flat >> 7;
        int rem = flat & 127;
        int wh  = rem >> 6;
        int e0  = rem & 63;
        int cw  = (wh << 6) | c;
        Wl[(e0 + 0) * WSTR + cw] = v.x;
        Wl[(e0 + 1) * WSTR + cw] = v.y;
        Wl[(e0 + 2) * WSTR + cw] = v.z;
        Wl[(e0 + 3) * WSTR + cw] = v.w;
    }
    // pair table: p -> (i, j), i<j, row-major triu order. S(i) = i*(77-i)/2.
    for (int idx = tid; idx < NPAIR; idx += 256) {
        int i = (int)floorf((77.0f - sqrtf(5929.0f - 8.0f * (float)idx)) * 0.5f);
        i = i < 0 ? 0 : (i > FDIM - 2 ? FDIM - 2 : i);
        while ((i + 1) * (77 - (i + 1)) / 2 <= idx) ++i;  // fixup for sqrt rounding
        while (i * (77 - i) / 2 > idx) --i;
        int j = idx - i * (77 - i) / 2 + i + 1;
        tab[idx] = i | (j << 8);
    }
    if (tid < CDIM) sbias[tid] = bias[tid];
    __syncthreads();

    // ---- phase 1: GEMM, per-thread 5f x 4cw tile ----
    const int ft  = tid >> 5;   // 0..7  -> f0 = ft*5 covers 0..39 (f=39 is pad, discarded)
    const int ct  = tid & 31;   // 0..31 -> cw0 = ct*4
    const int f0  = ft * 5;
    const int cw0 = ct * 4;

    float acc[5][4];
#pragma unroll
    for (int a = 0; a < 5; ++a)
#pragma unroll
        for (int q = 0; q < 4; ++q) acc[a][q] = 0.0f;

#pragma unroll 4
    for (int e = 0; e < EDIM; ++e) {
        float4 wv = *(const float4*)(Wl + e * WSTR + cw0);
        float xv[5];
#pragma unroll
        for (int a = 0; a < 5; ++a) xv[a] = xT[e * XSTR + f0 + a];
#pragma unroll
        for (int a = 0; a < 5; ++a) {
            acc[a][0] = fmaf(xv[a], wv.x, acc[a][0]);
            acc[a][1] = fmaf(xv[a], wv.y, acc[a][1]);
            acc[a][2] = fmaf(xv[a], wv.z, acc[a][2]);
            acc[a][3] = fmaf(xv[a], wv.w, acc[a][3]);
        }
    }
    __syncthreads();  // all reads of xT/Wl done before aliasing writes

    // ---- phase 1.5: write A[cw][f] ----
#pragma unroll
    for (int a = 0; a < 5; ++a)
#pragma unroll
        for (int q = 0; q < 4; ++q)
            A[(cw0 + q) * ASTR + (f0 + a)] = acc[a][q];
    __syncthreads();

    // ---- phase 2: gather + bias + relu + coalesced store ----
    float* outb = out + (size_t)b * (CDIM * NPAIR);
    for (int c = 0; c < CDIM; ++c) {
        const float bc = sbias[c];
        const float* rI = A + c * ASTR;          // Wi-dot row for channel c
        const float* rJ = A + (64 + c) * ASTR;   // Wj-dot row for channel c
        float* oc = outb + c * NPAIR;
        for (int p = tid; p < NPAIR; p += 256) {
            int t = tab[p];
            float v = rI[t & 0xff] + rJ[t >> 8] + bc;
            oc[p] = v > 0.0f ? v : 0.0f;
        }
    }
}

extern "C" void kernel_launch(void* const* d_in, const int* in_sizes, int n_in,
                              void* d_out, int out_size, void* d_ws, size_t ws_size,
                              hipStream_t stream) {
    const float* x    = (const float*)d_in[0];
    const float* W    = (const float*)d_in[1];
    const float* bias = (const float*)d_in[2];
    float* out        = (float*)d_out;

    interconv_fused<<<dim3(BATCH), dim3(256), 0, stream>>>(x, W, bias, out);
}